// Round 5
// baseline (274.846 us; speedup 1.0000x reference)
//
#include <hip/hip_runtime.h>
#include <stdint.h>

#define BATCH 32
#define SEQ   1024
#define DIM   64
#define NKT   (SEQ / 64)

typedef uint16_t u16;
typedef uint32_t u32;
typedef __attribute__((ext_vector_type(8))) __bf16 bf16x8;
typedef __attribute__((ext_vector_type(4))) float  f32x4;
typedef __attribute__((ext_vector_type(4))) u32    u32x4;

__device__ __forceinline__ u16 f2bf(float f) {
    u32 x = __builtin_bit_cast(u32, f);
    x += 0x7FFFu + ((x >> 16) & 1u);   // round-to-nearest-even
    return (u16)(x >> 16);
}

// 8 contiguous f32 -> bf16x8 fragment (RNE)
__device__ __forceinline__ bf16x8 cvt8(const float* __restrict__ p) {
    f32x4 a = *reinterpret_cast<const f32x4*>(p);
    f32x4 b = *reinterpret_cast<const f32x4*>(p + 4);
    u16 t[8];
    t[0] = f2bf(a[0]); t[1] = f2bf(a[1]); t[2] = f2bf(a[2]); t[3] = f2bf(a[3]);
    t[4] = f2bf(b[0]); t[5] = f2bf(b[1]); t[6] = f2bf(b[2]); t[7] = f2bf(b[3]);
    return __builtin_bit_cast(bf16x8, *reinterpret_cast<u32x4*>(t));
}

__device__ __forceinline__ bf16x8 ldg8(const u16* p) {
    u32x4 u = *reinterpret_cast<const u32x4*>(p);
    return __builtin_bit_cast(bf16x8, u);
}

// ---------------------------------------------------------------------------
// Kernel 1: V f32 [B][S][D] -> Vt bf16 [B][D][S], so PV B-fragments are
// contiguous 16B bf16 loads along k.
// ---------------------------------------------------------------------------
__global__ __launch_bounds__(256) void vt_kernel(const float* __restrict__ v,
                                                 u16* __restrict__ vt) {
    __shared__ u16 tile[64][72];  // +8 pad: kills transpose bank conflicts
    const int b  = blockIdx.y;
    const int k0 = blockIdx.x * 64;
    const int t  = threadIdx.x;
    const float* vb  = v  + (size_t)b * SEQ * DIM;
    u16*         vtb = vt + (size_t)b * DIM * SEQ;

    {   // load 64x64 f32 tile, convert, store bf16 to LDS
        int kk = t >> 2;           // 0..63
        int d0 = (t & 3) * 16;     // 0,16,32,48
        const float* src = vb + (size_t)(k0 + kk) * DIM + d0;
        u16 tmp[16];
#pragma unroll
        for (int i = 0; i < 4; ++i) {
            f32x4 a = *reinterpret_cast<const f32x4*>(src + i * 4);
            tmp[i * 4 + 0] = f2bf(a[0]); tmp[i * 4 + 1] = f2bf(a[1]);
            tmp[i * 4 + 2] = f2bf(a[2]); tmp[i * 4 + 3] = f2bf(a[3]);
        }
        *reinterpret_cast<u32x4*>(&tile[kk][d0])     = *reinterpret_cast<u32x4*>(tmp);
        *reinterpret_cast<u32x4*>(&tile[kk][d0 + 8]) = *reinterpret_cast<u32x4*>(tmp + 8);
    }
    __syncthreads();
#pragma unroll
    for (int i = 0; i < 2; ++i) {
        int d  = t / 8 + i * 32;
        int ks = (t % 8) * 8;
        u16 tmp[8];
#pragma unroll
        for (int j = 0; j < 8; ++j) tmp[j] = tile[ks + j][d];
        *reinterpret_cast<u32x4*>(vtb + (size_t)d * SEQ + k0 + ks) =
            *reinterpret_cast<u32x4*>(tmp);
    }
}

// ---------------------------------------------------------------------------
// Kernel 2: fused rel-pos attention, flash-style online softmax.
// One block = (batch b, 64 q-rows). 4 waves; wave w owns q-rows [w*16, w*16+16).
// All LDS regions are per-wave -> no __syncthreads in the K loop.
// Inputs f32 (converted to bf16 fragments in-register); OUTPUT IS F32.
// ---------------------------------------------------------------------------
template <bool USE_VT>
__global__ __launch_bounds__(256, 2) void attn_kernel(
    const float* __restrict__ qg, const float* __restrict__ kg,
    const void* __restrict__ vgv, const int* __restrict__ maskg,
    const float* __restrict__ ptg, float* __restrict__ outg) {
    // qp[row][j] = dot(q[row], pos_table[j]) (pre-scaling), j in [0,129)
    __shared__ float qp[64][132];        // 33792 B
    __shared__ int   mlds[4][16][68];    // 17408 B, per-wave mask tile
    __shared__ u16   plds[4][16][72];    //  9216 B, per-wave P tile (A-layout src)

    const int b    = blockIdx.y;
    const int q0   = blockIdx.x * 64;
    const int tid  = threadIdx.x;
    const int wave = tid >> 6;
    const int lane = tid & 63;
    const int quad = lane >> 4;   // 0..3
    const int c16  = lane & 15;   // 0..15

    const float* qb = qg + ((size_t)b * SEQ + q0) * DIM;
    const float* kb = kg + (size_t)b * SEQ * DIM;
    const int*   mb = maskg + ((size_t)b * SEQ + q0) * SEQ;

    // --- Q A-fragments (held for the whole kernel) -------------------------
    // A layout: lane holds A[m = c16][k = quad*8 + j (+32 for frag 1)]
    const bf16x8 qA0 = cvt8(qb + (size_t)(wave * 16 + c16) * DIM + quad * 8);
    const bf16x8 qA1 = cvt8(qb + (size_t)(wave * 16 + c16) * DIM + 32 + quad * 8);

    // --- qp table via MFMA: qp[64][129] = Q(64x64) . pos_table^T ----------
    for (int jt = 0; jt < 9; ++jt) {
        int j0 = jt * 16;
        int jr = min(j0 + c16, 128);  // clamp OOB rows; their cols are discarded
        bf16x8 b0 = cvt8(ptg + (size_t)jr * DIM + quad * 8);
        bf16x8 b1 = cvt8(ptg + (size_t)jr * DIM + 32 + quad * 8);
        f32x4 acc = {0.f, 0.f, 0.f, 0.f};
        acc = __builtin_amdgcn_mfma_f32_16x16x32_bf16(qA0, b0, acc, 0, 0, 0);
        acc = __builtin_amdgcn_mfma_f32_16x16x32_bf16(qA1, b1, acc, 0, 0, 0);
        int jcol = j0 + c16;
        if (jcol <= 128) {
#pragma unroll
            for (int r = 0; r < 4; ++r)
                qp[wave * 16 + quad * 4 + r][jcol] = acc[r];
        }
    }
    // per-wave LDS region; same-wave DS ordering is in-order -> no barrier

    float m_run[4], l_run[4];
    f32x4 O[4];
#pragma unroll
    for (int r = 0; r < 4; ++r) { m_run[r] = -1e30f; l_run[r] = 0.f; }
#pragma unroll
    for (int d = 0; d < 4; ++d) O[d] = f32x4{0.f, 0.f, 0.f, 0.f};

#pragma unroll 1
    for (int kt = 0; kt < NKT; ++kt) {
        const int k0 = kt * 64;

        // --- stage this wave's 16x64 mask tile, fully coalesced int4 -------
        {
            int row_l = lane >> 2;                      // 0..15
            const int* mrow = mb + (size_t)(wave * 16 + row_l) * SEQ + k0;
#pragma unroll
            for (int i = 0; i < 4; ++i) {
                int seg = (lane & 3) + i * 4;           // 0..15
                *reinterpret_cast<u32x4*>(&mlds[wave][row_l][seg * 4]) =
                    *reinterpret_cast<const u32x4*>(mrow + seg * 4);
            }
        }

        // --- S = Q . K^T (bf16 MFMA, fp32 acc) -----------------------------
        f32x4 S[4];
#pragma unroll
        for (int sub = 0; sub < 4; ++sub) {
            const float* kr = kb + (size_t)(k0 + sub * 16 + c16) * DIM;
            bf16x8 kb0 = cvt8(kr + quad * 8);
            bf16x8 kb1 = cvt8(kr + 32 + quad * 8);
            f32x4 acc = {0.f, 0.f, 0.f, 0.f};
            acc = __builtin_amdgcn_mfma_f32_16x16x32_bf16(qA0, kb0, acc, 0, 0, 0);
            acc = __builtin_amdgcn_mfma_f32_16x16x32_bf16(qA1, kb1, acc, 0, 0, 0);
            S[sub] = acc;
        }

        // --- logits: + rel-pos, * 1/8, mask -> -1e30 -----------------------
        float sv[4][4];  // [sub][r]
#pragma unroll
        for (int sub = 0; sub < 4; ++sub) {
#pragma unroll
            for (int r = 0; r < 4; ++r) {
                int row_l = quad * 4 + r;
                int row_g = q0 + wave * 16 + row_l;
                int col_g = k0 + sub * 16 + c16;
                int rel = col_g - row_g;
                rel = rel < -64 ? -64 : (rel > 64 ? 64 : rel);
                float x = (S[sub][r] + qp[wave * 16 + row_l][rel + 64]) * 0.125f;
                int mv = mlds[wave][row_l][sub * 16 + c16];
                sv[sub][r] = mv ? -1e30f : x;
            }
        }

        // --- online softmax (row spread across 16 lanes of the quad) -------
        float m_new[4], alpha[4];
#pragma unroll
        for (int r = 0; r < 4; ++r) {
            float rmax = fmaxf(fmaxf(sv[0][r], sv[1][r]), fmaxf(sv[2][r], sv[3][r]));
            rmax = fmaxf(rmax, __shfl_xor(rmax, 1));
            rmax = fmaxf(rmax, __shfl_xor(rmax, 2));
            rmax = fmaxf(rmax, __shfl_xor(rmax, 4));
            rmax = fmaxf(rmax, __shfl_xor(rmax, 8));
            m_new[r] = fmaxf(m_run[r], rmax);
            alpha[r] = __expf(m_run[r] - m_new[r]);  // all-masked corner self-corrects via alpha
            m_run[r] = m_new[r];
        }
#pragma unroll
        for (int r = 0; r < 4; ++r) {
            float rs = 0.f;
#pragma unroll
            for (int sub = 0; sub < 4; ++sub) {
                float e = __expf(sv[sub][r] - m_new[r]);  // masked -> exp(-huge)=0
                rs += e;
                plds[wave][quad * 4 + r][sub * 16 + c16] = f2bf(e);
            }
            rs += __shfl_xor(rs, 1);
            rs += __shfl_xor(rs, 2);
            rs += __shfl_xor(rs, 4);
            rs += __shfl_xor(rs, 8);
            l_run[r] = l_run[r] * alpha[r] + rs;
#pragma unroll
            for (int d = 0; d < 4; ++d) O[d][r] *= alpha[r];
        }

        // --- P (A-layout from LDS) and PV accumulate -----------------------
        bf16x8 pA0 = *reinterpret_cast<bf16x8*>(&plds[wave][c16][quad * 8]);
        bf16x8 pA1 = *reinterpret_cast<bf16x8*>(&plds[wave][c16][32 + quad * 8]);
#pragma unroll
        for (int d = 0; d < 4; ++d) {
            bf16x8 vb0, vb1;
            if (USE_VT) {
                const u16* vtb = (const u16*)vgv + (size_t)b * DIM * SEQ +
                                 (size_t)(d * 16 + c16) * SEQ + k0;
                vb0 = ldg8(vtb + quad * 8);
                vb1 = ldg8(vtb + 32 + quad * 8);
            } else {
                u16 t0[8], t1[8];
                const float* vbase = (const float*)vgv +
                                     ((size_t)b * SEQ + k0) * DIM + d * 16 + c16;
#pragma unroll
                for (int j = 0; j < 8; ++j) {
                    t0[j] = f2bf(vbase[(size_t)(quad * 8 + j) * DIM]);
                    t1[j] = f2bf(vbase[(size_t)(32 + quad * 8 + j) * DIM]);
                }
                vb0 = __builtin_bit_cast(bf16x8, *reinterpret_cast<u32x4*>(t0));
                vb1 = __builtin_bit_cast(bf16x8, *reinterpret_cast<u32x4*>(t1));
            }
            O[d] = __builtin_amdgcn_mfma_f32_16x16x32_bf16(pA0, vb0, O[d], 0, 0, 0);
            O[d] = __builtin_amdgcn_mfma_f32_16x16x32_bf16(pA1, vb1, O[d], 0, 0, 0);
        }
    }

    // --- epilogue: out = O / l, FLOAT32 ------------------------------------
    float* ob = outg + ((size_t)b * SEQ + q0) * DIM;
#pragma unroll
    for (int r = 0; r < 4; ++r) {
        float inv = 1.f / l_run[r];
        int row_l = wave * 16 + quad * 4 + r;
#pragma unroll
        for (int d = 0; d < 4; ++d)
            ob[(size_t)row_l * DIM + d * 16 + c16] = O[d][r] * inv;
    }
}

// ---------------------------------------------------------------------------
extern "C" void kernel_launch(void* const* d_in, const int* in_sizes, int n_in,
                              void* d_out, int out_size, void* d_ws, size_t ws_size,
                              hipStream_t stream) {
    const float* q    = (const float*)d_in[0];
    const float* k    = (const float*)d_in[1];
    const float* v    = (const float*)d_in[2];
    const int*   mask = (const int*)d_in[3];
    const float* pt   = (const float*)d_in[4];
    float* out        = (float*)d_out;

    const size_t vt_bytes = (size_t)BATCH * SEQ * DIM * sizeof(u16);
    dim3 grid(SEQ / 64, BATCH);

    if (ws_size >= vt_bytes) {
        u16* vt = (u16*)d_ws;
        vt_kernel<<<grid, 256, 0, stream>>>(v, vt);
        attn_kernel<true><<<grid, 256, 0, stream>>>(q, k, (const void*)vt, mask, pt, out);
    } else {
        attn_kernel<false><<<grid, 256, 0, stream>>>(q, k, (const void*)v, mask, pt, out);
    }
}